// Round 15
// baseline (136.273 us; speedup 1.0000x reference)
//
#include <hip/hip_runtime.h>
#include <math.h>

typedef _Float16 f16;
typedef _Float16 f16x8 __attribute__((ext_vector_type(8)));
typedef _Float16 f16x4 __attribute__((ext_vector_type(4)));
typedef float f32x4 __attribute__((ext_vector_type(4)));

#define B_  4
#define N_  2048
#define C_  128
#define NS_ 64

// ---- workspace layout (bytes) ----
#define WS_FEAT16 0u          // B*N*C f16 = 2097152
#define WS_IDX    2097152u    // B*N*NS u16 = 1048576
#define WS_W1X    3145728u    // [256 o][8 slots] = 8192
#define WS_W1P    3153920u    // 4 slices * 16384 = 65536
#define WS_W2P    3219456u    // 4 slices * 16384 = 65536

// ---- mlp LDS layout (bytes), total 53248 -> 3 blocks/CU ----
#define OFF_H   0             // h: 4 groups x 4096 = 16384 (a1 halves overlay)
#define OFF_HX  16384         // xyz half-group [64 s][32B] = 2048
#define OFF_W   18432         // weight dbuf 2 x 16384 (ends 51200)
#define OFF_A2  0             // 64*528 = 33792 f32 (overlays H/HX/W at the end)
#define OFF_GX  51200         // [64][3] f32 = 768
#define OFF_QF  51968         // [128] f16 = 256 (512 reserved)
#define OFF_IDX 52480         // 256 (RED overlays after gather)
#define OFF_RED 52480
#define OFF_W3  52736         // 512
#define LDS_TOTAL 53248

__device__ __forceinline__ void gl_lds16(const char* gp, char* lp) {
  __builtin_amdgcn_global_load_lds(
      (const __attribute__((address_space(1))) unsigned int*)gp,
      (__attribute__((address_space(3))) unsigned int*)lp, 16, 0, 0);
}

// pack two floats as adjacent f16 (RTN)
__device__ __forceinline__ unsigned pk2(float a, float b) {
  union { f16 h[2]; unsigned u; } cv;
  cv.h[0] = (f16)a; cv.h[1] = (f16)b;
  return cv.u;
}

// ---------------------------------------------------------------------------
// prep: feat (B,C,N) f32 -> feat16 (B,N,C) f16. BN gains folded into weights:
// W1 cols scaled by g1[o]*inv, W2 by g2[p]*inv (biases enter as MFMA C-init).
// W1 feature-cols -> 4 K-slices (32 ch) [256 o][16 pair-slots] swizzled
// ((o>>1)&7)<<4 (64B rows); W1 xyz-cols -> [256 o][8 slots] linear; W2 -> 4
// K-slices (64 ch) [128 p][32 slots] swizzled ((p&7))<<4 (128B rows, G4).
// ---------------------------------------------------------------------------
__global__ __launch_bounds__(256) void prep_kernel(
    const float* __restrict__ feat, const float* __restrict__ W1,
    const float* __restrict__ W2,
    const float* __restrict__ g1, const float* __restrict__ g2,
    f16* __restrict__ feat16,
    char* __restrict__ W1x, char* __restrict__ W1p, char* __restrict__ W2p)
{
  const float inv = 1.0f / sqrtf(1.0f + 1e-5f);
  int i = blockIdx.x * 256 + threadIdx.x;
  {
    int n = i & (N_ - 1);
    int bc = i >> 11;
    int c = bc & (C_ - 1);
    int b = bc >> 7;
    feat16[(size_t)((b << 11) + n) * C_ + c] = (f16)feat[i];
  }
  if (i < 16384) {   // W1 feature: g slice, [o 0..255][j 0..15]; ch = 3+32g+2j
    int g = i >> 12, r = i & 4095, o = r >> 4, j = r & 15;
    float sc = g1[o] * inv;
    const float* row = W1 + o * 131 + 3 + g * 32 + 2 * j;
    unsigned byte = ((unsigned)(o * 64 + j * 4)) ^ ((unsigned)(((o >> 1) & 7) << 4));
    *(unsigned*)(W1p + (size_t)g * 16384 + byte) = pk2(row[0] * sc, row[1] * sc);
  }
  if (i < 16384) {   // W2: ko slice, [p 0..127][j 0..31]; o = 64ko+2j
    int ko = i >> 12, r = i & 4095, p = r >> 5, j = r & 31;
    float sc = g2[p] * inv;
    int o = ko * 64 + 2 * j;
    unsigned byte = ((unsigned)(p * 128 + j * 4)) ^ ((unsigned)((p & 7) << 4));
    *(unsigned*)(W2p + (size_t)ko * 16384 + byte) =
        pk2(W2[p * 256 + o] * sc, W2[p * 256 + o + 1] * sc);
  }
  if (i < 2048) {    // W1 xyz: [256 o][8 slots] linear, scaled
    int o = i >> 3, j = i & 7;
    float sc = g1[o] * inv;
    unsigned v = 0;
    if (j == 0)      v = pk2(W1[o * 131 + 0] * sc, W1[o * 131 + 1] * sc);
    else if (j == 1) v = pk2(W1[o * 131 + 2] * sc, 0.0f);
    *(unsigned*)(W1x + o * 32 + j * 4) = v;
  }
}

// ---------------------------------------------------------------------------
// ball query (fp64-exact membership), output u16
// ---------------------------------------------------------------------------
__global__ __launch_bounds__(256) void ballquery_kernel(
    const float* __restrict__ xyz, unsigned short* __restrict__ idxout)
{
  __shared__ float  xl[N_ * 3];
  __shared__ double sq[N_];
  __shared__ int    ibuf[4][NS_];

  const int b  = blockIdx.x >> 9;
  const int ng = blockIdx.x & 511;
  const int t  = threadIdx.x;
  const float* xb = xyz + (size_t)b * N_ * 3;

  for (int i = t; i < N_ * 3; i += 256) xl[i] = xb[i];
  __syncthreads();
  for (int i = t; i < N_; i += 256) {
    double x = (double)xl[3*i], y = (double)xl[3*i+1], z = (double)xl[3*i+2];
    sq[i] = x*x + y*y + z*z;
  }
  __syncthreads();

  const int wv = t >> 6, lane = t & 63;
  const int n = ng * 4 + wv;
  const double xn = (double)xl[3*n], yn = (double)xl[3*n+1], zn = (double)xl[3*n+2];
  const double sn = sq[n];

  int cnt = 0;
  for (int mb = 0; mb < N_; mb += 64) {
    int m = mb + lane;
    double dot = xn*(double)xl[3*m] + yn*(double)xl[3*m+1] + zn*(double)xl[3*m+2];
    double d2 = (sn + sq[m]) - 2.0 * dot;
    bool hit = d2 < 0.0625;
    unsigned long long mask = __ballot(hit);
    int pos = __popcll(mask & ((1ULL << lane) - 1ULL));
    int slot = cnt + pos;
    if (hit && slot < NS_) ibuf[wv][slot] = m;
    cnt += (int)__popcll(mask);
    if (cnt >= NS_) break;
  }
  asm volatile("s_waitcnt lgkmcnt(0)" ::: "memory");
  int total = cnt < NS_ ? cnt : NS_;
  int v = ibuf[wv][lane < total ? lane : 0];
  idxout[((size_t)b * N_ + n) * NS_ + lane] = (unsigned short)v;
}

// ---------------------------------------------------------------------------
// MLP: pure-f16 MFMA, 9 phases, ONE barrier per phase. Phase = {vmcnt(0)+
// lgkm(0); bar; STAGE(next); frag reads; MFMA}. STAGE after the barrier makes
// the dbuf overwrite safe (phase p-1 reads are consumed by MFMA issue before
// any wave passes bar(p)); the staged slice drains one full phase later.
// BN folded: weights pre-scaled by g*inv, biases via MFMA C-operand init.
// Phase 0: xyz K=16 (inits acc1 = b1). Phases 1-4: GEMM1 K=32. Phases 5-8:
// GEMM2 K=64 (acc2 init = b2), a1 half-split. 53248B LDS -> 3 blocks/CU.
// ---------------------------------------------------------------------------
__global__ __launch_bounds__(256, 3) void mlp_kernel(
    const float* __restrict__ xyz, const f16* __restrict__ feat16,
    const char* __restrict__ w1x, const char* __restrict__ w1p,
    const char* __restrict__ w2p,
    const unsigned short* __restrict__ idxg,
    const float* __restrict__ W3g,
    const float* __restrict__ b1,
    const float* __restrict__ b2,
    const float* __restrict__ g3, const float* __restrict__ b3,
    float* __restrict__ out)
{
  __shared__ __attribute__((aligned(128))) char lds[LDS_TOTAL];

  const int bidRaw = blockIdx.x;
  const int bn = ((bidRaw & 7) << 10) + (bidRaw >> 3);   // XCD swizzle (bijective)
  const int b = bn >> 11;
  const int n = bn & (N_ - 1);
  const int t = threadIdx.x;
  const int w = t >> 6, lane = t & 63;
  const int l15 = lane & 15, lg = lane >> 4;
  const unsigned swzl = (unsigned)(((l15 >> 1) & 7) << 4);
  const unsigned labase = ((unsigned)(l15 * 64 + lg * 16)) ^ swzl;
  const unsigned swz2 = (unsigned)((l15 & 7) << 4);
  const unsigned w2b0 = ((unsigned)(l15 * 128 + lg * 16)) ^ swz2;        // k 0..31
  const unsigned w2b1 = ((unsigned)(l15 * 128 + 64 + lg * 16)) ^ swz2;   // k 32..63
  const float inv = 1.0f / sqrtf(1.0f + 1e-5f);

  float bo1v[4];
  #pragma unroll
  for (int nt = 0; nt < 4; ++nt) {
    int o = (nt >> 1) * 128 + 32 * w + (nt & 1) * 16 + l15;
    bo1v[nt] = b1[o];
  }
  float bo2v[2];
  #pragma unroll
  for (int nt = 0; nt < 2; ++nt) {
    int p = 32 * w + nt * 16 + l15;
    bo2v[nt] = b2[p];
  }
  const float g3c = g3[0] * inv, b3c = b3[0];
  const float xn0 = xyz[(size_t)bn*3+0], xn1 = xyz[(size_t)bn*3+1], xn2 = xyz[(size_t)bn*3+2];

  // slices: 0 = W1x (8KB, 2 loads), 1..4 = W1 g (16KB, 4), 5..8 = W2 k (16KB, 4)
  auto STAGE = [&](int sl) {
    const char* gp; int nloads;
    if (sl == 0)      { gp = w1x;                          nloads = 2; }
    else if (sl <= 4) { gp = w1p + (size_t)(sl - 1) * 16384; nloads = 4; }
    else              { gp = w2p + (size_t)(sl - 5) * 16384; nloads = 4; }
    gp += t * 16;
    char* lp = lds + OFF_W + ((sl & 1) << 14) + (w << 10);
    for (int i = 0; i < nloads; ++i)
      gl_lds16(gp + i * 4096, lp + i * 4096);
  };

  f32x4 acc1[4][4];
  f32x4 acc2[4][2];
  #pragma unroll
  for (int mt = 0; mt < 4; ++mt)
    #pragma unroll
    for (int nt2 = 0; nt2 < 2; ++nt2) {
      f32x4 c = {bo2v[nt2], bo2v[nt2], bo2v[nt2], bo2v[nt2]};
      acc2[mt][nt2] = c;
    }

  // ---- prologue ----
  STAGE(0);
  if (t < 64) ((int*)(lds + OFF_IDX))[t] = (int)idxg[(size_t)bn * 64 + t];
  if (t < 64) ((unsigned*)(lds + OFF_QF))[t] =
      ((const unsigned*)(feat16 + (size_t)bn * C_))[t];
  if (t < 128) ((float*)(lds + OFF_W3))[t] = W3g[t] * g3c;
  __syncthreads();

  const int* idxl = (const int*)(lds + OFF_IDX);

  // feature gather: h = (p16 - q16)^2 packed f16; thread t -> (s = t&63, g = t>>6)
  {
    int s = t & 63, g = t >> 6;
    int m = idxl[s];
    const f16* pb = feat16 + ((size_t)b * N_ + m) * C_ + g * 32;
    const f16* qb = (const f16*)(lds + OFF_QF) + g * 32;
    const unsigned sw = ((unsigned)((s >> 1) & 7)) << 4;
    const unsigned base = (unsigned)(g * 4096);
    #pragma unroll
    for (int qq = 0; qq < 4; ++qq) {
      f16x8 p = *(const f16x8*)(pb + qq * 8);
      f16x8 q = *(const f16x8*)(qb + qq * 8);
      f16x8 d = p - q;
      f16x8 hh = d * d;
      unsigned byte = base
        + ((((unsigned)(s * 64 + qq * 16)) ^ sw ^ ((unsigned)((g & 3) << 4))));
      *(f16x8*)(lds + OFF_H + byte) = hh;
    }
  }
  // xyz gather: GX (f32 relative) + hx half-group (f16)
  if (t < 64) {
    int s = t;
    int m = idxl[s];
    const float* pm = xyz + ((size_t)b * N_ + m) * 3;
    float p0 = pm[0], p1 = pm[1], p2c = pm[2];
    float* gxp = (float*)(lds + OFF_GX) + s * 3;
    gxp[0] = p0 - xn0; gxp[1] = p1 - xn1; gxp[2] = p2c - xn2;
    float h0 = p0 - 2.0f * xn0; h0 *= h0;
    float h1 = p1 - 2.0f * xn1; h1 *= h1;
    float h2 = p2c - 2.0f * xn2; h2 *= h2;
    char* hx = lds + OFF_HX + s * 32;
    *(unsigned*)(hx + 0)  = pk2(h0, h1);
    *(unsigned*)(hx + 4)  = pk2(h2, 0.0f);
    *(unsigned*)(hx + 8)  = 0u;
    *(unsigned*)(hx + 12) = 0u;
    f32x4 z4 = {0.0f, 0.0f, 0.0f, 0.0f};
    *(f32x4*)(hx + 16) = z4;
  }

  // ---- phase 0: xyz K=16 (reads hx + W1x in buf0), acc1 = b1 + xyz-contrib ----
  asm volatile("s_waitcnt vmcnt(0) lgkmcnt(0)" ::: "memory");
  __builtin_amdgcn_s_barrier();
  STAGE(1);
  {
    const char* wbx = lds + OFF_W;   // buf0, first 8KB
    f16x4 bf4[4];
    #pragma unroll
    for (int nt = 0; nt < 4; ++nt) {
      int orow = (nt >> 1) * 128 + 32 * w + (nt & 1) * 16 + l15;
      bf4[nt] = *(const f16x4*)(wbx + orow * 32 + lg * 8);
    }
    f16x4 af4[4];
    #pragma unroll
    for (int mt = 0; mt < 4; ++mt)
      af4[mt] = *(const f16x4*)(lds + OFF_HX + (16 * mt + l15) * 32 + lg * 8);
    #pragma unroll
    for (int mt = 0; mt < 4; ++mt)
      #pragma unroll
      for (int nt = 0; nt < 4; ++nt) {
        f32x4 cb = {bo1v[nt], bo1v[nt], bo1v[nt], bo1v[nt]};
        acc1[mt][nt] = __builtin_amdgcn_mfma_f32_16x16x16f16(af4[mt], bf4[nt], cb, 0, 0, 0);
      }
  }

  // ---- phases 1..4: GEMM1 K=32 each, all 256 o ----
  #pragma unroll
  for (int g = 0; g < 4; ++g) {
    const int sl = 1 + g;
    asm volatile("s_waitcnt vmcnt(0) lgkmcnt(0)" ::: "memory");
    __builtin_amdgcn_s_barrier();
    STAGE(sl + 1);
    const char* wb = lds + OFF_W + ((sl & 1) << 14);
    f16x8 bf[4];
    #pragma unroll
    for (int nt = 0; nt < 4; ++nt) {
      int ob = (nt >> 1) * 128 + 32 * w + (nt & 1) * 16;
      bf[nt] = *(const f16x8*)(wb + ob * 64 + labase);
    }
    const char* hb = lds + OFF_H + g * 4096;
    const unsigned gx4 = ((unsigned)g) << 4;
    f16x8 af[4];
    #pragma unroll
    for (int mt = 0; mt < 4; ++mt)
      af[mt] = *(const f16x8*)(hb + mt * 1024 + (labase ^ gx4));
    __builtin_amdgcn_s_setprio(1);
    #pragma unroll
    for (int mt = 0; mt < 4; ++mt)
      #pragma unroll
      for (int nt = 0; nt < 4; ++nt)
        acc1[mt][nt] = __builtin_amdgcn_mfma_f32_16x16x32_f16(af[mt], bf[nt], acc1[mt][nt], 0, 0, 0);
    __builtin_amdgcn_s_setprio(0);
  }

  // ---- epilogue1: a1 = relu(acc1) (BN pre-folded) -> h slots; wave w -> slot w ----
  auto EPI1 = [&](int hf) {
    #pragma unroll
    for (int mt = 0; mt < 4; ++mt)
      #pragma unroll
      for (int nt2 = 0; nt2 < 2; ++nt2) {
        const int nt = hf * 2 + nt2;
        #pragma unroll
        for (int r = 0; r < 4; ++r) {
          int s = mt * 16 + lg * 4 + r;
          float a = acc1[mt][nt][r];
          a = a > 0.0f ? a : 0.0f;
          unsigned byte = (unsigned)(w * 4096)
            + (((unsigned)(s * 64 + nt2 * 32 + l15 * 2)) ^ ((unsigned)(((s >> 1) & 7) << 4))
               ^ ((unsigned)((w & 3) << 4)));
          *(f16*)(lds + OFF_H + byte) = (f16)a;
        }
      }
  };
  asm volatile("s_waitcnt lgkmcnt(0)" ::: "memory");   // all h reads done
  __builtin_amdgcn_s_barrier();
  EPI1(0);

  // ---- phases 5..8: GEMM2 K=64 each, a1 half-split after k==1 ----
  #pragma unroll
  for (int k = 0; k < 4; ++k) {
    const int sl = 5 + k;
    asm volatile("s_waitcnt vmcnt(0) lgkmcnt(0)" ::: "memory");
    __builtin_amdgcn_s_barrier();
    if (sl < 8) STAGE(sl + 1);
    const char* wb = lds + OFF_W + ((sl & 1) << 14);
    f16x8 bq0[2], bq1[2];
    #pragma unroll
    for (int nt2 = 0; nt2 < 2; ++nt2) {
      int pb = (32 * w + nt2 * 16) * 128;
      bq0[nt2] = *(const f16x8*)(wb + pb + w2b0);
      bq1[nt2] = *(const f16x8*)(wb + pb + w2b1);
    }
    const int sl0 = (2 * k) & 3, sl1 = (2 * k + 1) & 3;
    f16x8 a0f[4], a1f[4];
    #pragma unroll
    for (int mt = 0; mt < 4; ++mt) {
      a0f[mt] = *(const f16x8*)(lds + OFF_H + sl0 * 4096 + mt * 1024 + (labase ^ (unsigned)(sl0 << 4)));
      a1f[mt] = *(const f16x8*)(lds + OFF_H + sl1 * 4096 + mt * 1024 + (labase ^ (unsigned)(sl1 << 4)));
    }
    __builtin_amdgcn_s_setprio(1);
    #pragma unroll
    for (int mt = 0; mt < 4; ++mt)
      #pragma unroll
      for (int nt2 = 0; nt2 < 2; ++nt2) {
        f32x4 c = acc2[mt][nt2];
        c = __builtin_amdgcn_mfma_f32_16x16x32_f16(a0f[mt], bq0[nt2], c, 0, 0, 0);
        c = __builtin_amdgcn_mfma_f32_16x16x32_f16(a1f[mt], bq1[nt2], c, 0, 0, 0);
        acc2[mt][nt2] = c;
      }
    __builtin_amdgcn_s_setprio(0);
    if (k == 1) {   // slots 0..3 (a1 half0) consumed -> write half1 (o 128..255)
      asm volatile("s_waitcnt lgkmcnt(0)" ::: "memory");
      __builtin_amdgcn_s_barrier();
      EPI1(1);
    }
  }
  asm volatile("s_waitcnt lgkmcnt(0)" ::: "memory");   // phase8 a-reads done
  __builtin_amdgcn_s_barrier();

  // ---- epilogue2: a2 = relu(acc2) f32, rows stride 528B (overlays H/W) ----
  #pragma unroll
  for (int mt = 0; mt < 4; ++mt)
    #pragma unroll
    for (int nt2 = 0; nt2 < 2; ++nt2) {
      int p2 = 32 * w + nt2 * 16 + l15;
      #pragma unroll
      for (int r = 0; r < 4; ++r) {
        int s = mt * 16 + lg * 4 + r;
        float a = acc2[mt][nt2][r];
        a = a > 0.0f ? a : 0.0f;
        *(float*)(lds + OFF_A2 + s * 528 + p2 * 4) = a;
      }
    }
  asm volatile("s_waitcnt lgkmcnt(0)" ::: "memory");
  __builtin_amdgcn_s_barrier();

  // ---- GEMM3 (W3 pre-scaled by g3*inv) + weighted mean ----
  {
    int s3 = t >> 2, q3 = t & 3;
    const float* a2row = (const float*)(lds + OFF_A2) + s3 * 132;
    const float* w3r = (const float*)(lds + OFF_W3);
    float z3 = 0.0f;
    #pragma unroll
    for (int i = 0; i < 8; ++i) {
      f32x4 av = *(const f32x4*)(a2row + q3 * 32 + i * 4);
      f32x4 wv = *(const f32x4*)(w3r + q3 * 32 + i * 4);
      z3 = fmaf(av[0], wv[0], z3); z3 = fmaf(av[1], wv[1], z3);
      z3 = fmaf(av[2], wv[2], z3); z3 = fmaf(av[3], wv[3], z3);
    }
    z3 += __shfl_xor(z3, 1);
    z3 += __shfl_xor(z3, 2);
    float wgt = z3 + b3c;
    wgt = wgt > 0.0f ? wgt : 0.0f;
    float v0 = 0.f, v1 = 0.f, v2 = 0.f, v3 = 0.f;
    if (q3 == 0) {
      const float* gx = (const float*)(lds + OFF_GX) + s3 * 3;
      v0 = gx[0] * wgt; v1 = gx[1] * wgt; v2 = gx[2] * wgt; v3 = wgt;
    }
    #pragma unroll
    for (int off = 4; off < 64; off <<= 1) {
      v0 += __shfl_xor(v0, off); v1 += __shfl_xor(v1, off);
      v2 += __shfl_xor(v2, off); v3 += __shfl_xor(v3, off);
    }
    if (lane == 0) {
      float* red = (float*)(lds + OFF_RED);
      red[w * 4 + 0] = v0; red[w * 4 + 1] = v1;
      red[w * 4 + 2] = v2; red[w * 4 + 3] = v3;
    }
    __syncthreads();
    if (t == 0) {
      const float* red = (const float*)(lds + OFF_RED);
      float n0 = red[0] + red[4] + red[8]  + red[12];
      float n1 = red[1] + red[5] + red[9]  + red[13];
      float n2 = red[2] + red[6] + red[10] + red[14];
      float dd = red[3] + red[7] + red[11] + red[15];
      out[(size_t)(b * 3 + 0) * N_ + n] = n0 / dd;
      out[(size_t)(b * 3 + 1) * N_ + n] = n1 / dd;
      out[(size_t)(b * 3 + 2) * N_ + n] = n2 / dd;
    }
  }
}

extern "C" void kernel_launch(void* const* d_in, const int* in_sizes, int n_in,
                              void* d_out, int out_size, void* d_ws, size_t ws_size,
                              hipStream_t stream) {
  (void)in_sizes; (void)n_in; (void)out_size; (void)ws_size;
  const float* xyz      = (const float*)d_in[0];
  const float* features = (const float*)d_in[1];
  const float* W1 = (const float*)d_in[2];
  const float* W2 = (const float*)d_in[3];
  const float* W3 = (const float*)d_in[4];
  const float* g1 = (const float*)d_in[5];
  const float* g2 = (const float*)d_in[6];
  const float* g3 = (const float*)d_in[7];
  const float* b1 = (const float*)d_in[8];
  const float* b2 = (const float*)d_in[9];
  const float* b3 = (const float*)d_in[10];
  float* out = (float*)d_out;

  char* ws = (char*)d_ws;
  f16* feat16         = (f16*)(ws + WS_FEAT16);
  unsigned short* idx = (unsigned short*)(ws + WS_IDX);
  char* W1x           = ws + WS_W1X;
  char* W1p           = ws + WS_W1P;
  char* W2p           = ws + WS_W2P;

  prep_kernel<<<dim3((B_ * C_ * N_) / 256), dim3(256), 0, stream>>>(
      features, W1, W2, g1, g2, feat16, W1x, W1p, W2p);
  ballquery_kernel<<<dim3(B_ * N_ / 4), dim3(256), 0, stream>>>(xyz, idx);
  mlp_kernel<<<dim3(B_ * N_), dim3(256), 0, stream>>>(
      xyz, feat16, W1x, W1p, W2p, idx, W3, b1, b2, g3, b3, out);
}